// Round 1
// baseline (1328.493 us; speedup 1.0000x reference)
//
#include <hip/hip_runtime.h>
#include <math.h>

#define B_ 64
#define T_ 1024
#define D_ 512
#define U_ 1024

#define TB 64    // t-rows per block tile
#define TUC 64   // u per chunk
#define TK 32    // k (d) tile
#define NSEG 4   // t-segments for context partials

__device__ __forceinline__ float fast_tanh(float x) {
    float ax = fabsf(x);
    float e = __expf(2.0f * ax);          // v_exp_f32-based
    float r = 1.0f - __fdividef(2.0f, e + 1.0f); // saturates cleanly: e=inf -> r=1
    return copysignf(r, x);
}

// K1: ph[b][u] = hidden[b,:]·W2[:,u] + W2_b[u] + W1_b[u]
// grid (U/256, B/8), block 256
__global__ __launch_bounds__(256) void ph_kernel(
    const float* __restrict__ hidden, const float* __restrict__ W2,
    const float* __restrict__ W2b, const float* __restrict__ W1b,
    float* __restrict__ ph) {
    const int u = blockIdx.x * 256 + threadIdx.x;
    const int b0 = blockIdx.y * 8;
    float acc[8];
#pragma unroll
    for (int i = 0; i < 8; ++i) acc[i] = 0.f;
    for (int d = 0; d < D_; ++d) {
        const float w = W2[d * U_ + u];
#pragma unroll
        for (int i = 0; i < 8; ++i)
            acc[i] = fmaf(hidden[(b0 + i) * D_ + d], w, acc[i]);
    }
    const float bias = W2b[u] + W1b[u];
#pragma unroll
    for (int i = 0; i < 8; ++i) ph[(b0 + i) * U_ + u] = acc[i] + bias;
}

// K2: fused GEMM + tanh + V-dot -> logits[b][t]
// grid (T/TB, B), block 256 (conceptually 16x16, each thread 4x4 micro-tile)
__global__ __launch_bounds__(256) void logits_kernel(
    const float* __restrict__ feat,   // [B,T,D]
    const float* __restrict__ W1,     // [D,U]
    const float* __restrict__ ph,     // [B,U] (biases folded)
    const float* __restrict__ Vw,     // [U]
    const float* __restrict__ Vb,     // [1]
    float* __restrict__ logits) {     // [B,T]
    __shared__ float Fs[TK][TB];      // [k][row]  (transposed tile)
    __shared__ float Ws[TK][TUC];     // [k][u]

    const int b   = blockIdx.y;
    const int t0  = blockIdx.x * TB;
    const int tid = threadIdx.x;
    const int tx  = tid & 15;   // u direction
    const int ty  = tid >> 4;   // row direction

    // staging index precompute
    const int frow  = tid >> 3;        // 0..31 (row within tile, pass adds 32)
    const int fcol4 = (tid & 7) * 4;   // 0..28 (k within tile)
    const int wk    = tid >> 4;        // 0..15 (k, pass adds 16)
    const int wu4   = (tid & 15) * 4;  // 0..60 (u within chunk)

    float lp[4] = {0.f, 0.f, 0.f, 0.f};  // per-row logit partials (rows 4*ty+i)

    for (int uc = 0; uc < U_; uc += TUC) {
        float acc[4][4];
#pragma unroll
        for (int i = 0; i < 4; ++i)
#pragma unroll
            for (int j = 0; j < 4; ++j) acc[i][j] = 0.f;

        for (int kc = 0; kc < D_; kc += TK) {
            __syncthreads();  // previous tile's readers done before overwrite
#pragma unroll
            for (int p = 0; p < 2; ++p) {
                const int r = frow + p * 32;
                const float4 v = *(const float4*)&feat[((size_t)b * T_ + t0 + r) * D_ + kc + fcol4];
                Fs[fcol4 + 0][r] = v.x;
                Fs[fcol4 + 1][r] = v.y;
                Fs[fcol4 + 2][r] = v.z;
                Fs[fcol4 + 3][r] = v.w;
            }
#pragma unroll
            for (int p = 0; p < 2; ++p) {
                const int k = wk + p * 16;
                *(float4*)&Ws[k][wu4] =
                    *(const float4*)&W1[(size_t)(kc + k) * U_ + uc + wu4];
            }
            __syncthreads();
#pragma unroll
            for (int k = 0; k < TK; ++k) {
                const float4 a = *(const float4*)&Fs[k][ty * 4];
                const float4 w = *(const float4*)&Ws[k][tx * 4];
                acc[0][0] = fmaf(a.x, w.x, acc[0][0]);
                acc[0][1] = fmaf(a.x, w.y, acc[0][1]);
                acc[0][2] = fmaf(a.x, w.z, acc[0][2]);
                acc[0][3] = fmaf(a.x, w.w, acc[0][3]);
                acc[1][0] = fmaf(a.y, w.x, acc[1][0]);
                acc[1][1] = fmaf(a.y, w.y, acc[1][1]);
                acc[1][2] = fmaf(a.y, w.z, acc[1][2]);
                acc[1][3] = fmaf(a.y, w.w, acc[1][3]);
                acc[2][0] = fmaf(a.z, w.x, acc[2][0]);
                acc[2][1] = fmaf(a.z, w.y, acc[2][1]);
                acc[2][2] = fmaf(a.z, w.z, acc[2][2]);
                acc[2][3] = fmaf(a.z, w.w, acc[2][3]);
                acc[3][0] = fmaf(a.w, w.x, acc[3][0]);
                acc[3][1] = fmaf(a.w, w.y, acc[3][1]);
                acc[3][2] = fmaf(a.w, w.z, acc[3][2]);
                acc[3][3] = fmaf(a.w, w.w, acc[3][3]);
            }
        }
        // epilogue for this u-chunk: tanh + V-weight, fold into row partials
#pragma unroll
        for (int j = 0; j < 4; ++j) {
            const int u = uc + tx * 4 + j;
            const float phv = ph[b * U_ + u];
            const float vw  = Vw[u];
#pragma unroll
            for (int i = 0; i < 4; ++i) {
                const float s = fast_tanh(acc[i][j] + phv);
                lp[i] = fmaf(vw, s, lp[i]);
            }
        }
    }

    // reduce lp across the 16 tx-threads sharing each row (reuse Fs as scratch)
    __syncthreads();
    float* red = &Fs[0][0];  // 64 rows x 16 partials
#pragma unroll
    for (int i = 0; i < 4; ++i) red[(ty * 4 + i) * 16 + tx] = lp[i];
    __syncthreads();
    if (tid < 64) {
        float s = 0.f;
#pragma unroll
        for (int x = 0; x < 16; ++x) s += red[tid * 16 + x];
        logits[b * T_ + t0 + tid] = s + Vb[0];
    }
}

// K3: softmax over T per batch. grid B, block 256 (4 elems/thread)
__global__ __launch_bounds__(256) void softmax_kernel(
    const float* __restrict__ logits, float* __restrict__ attn) {
    const int b = blockIdx.x;
    const int tid = threadIdx.x;
    __shared__ float redm[4];
    __shared__ float reds[4];
    const float* lr = logits + b * T_;
    float v[4];
    float mx = -3.4e38f;
#pragma unroll
    for (int j = 0; j < 4; ++j) {
        v[j] = lr[tid + 256 * j];
        mx = fmaxf(mx, v[j]);
    }
#pragma unroll
    for (int off = 32; off > 0; off >>= 1) mx = fmaxf(mx, __shfl_xor(mx, off));
    if ((tid & 63) == 0) redm[tid >> 6] = mx;
    __syncthreads();
    mx = fmaxf(fmaxf(redm[0], redm[1]), fmaxf(redm[2], redm[3]));
    float s = 0.f;
#pragma unroll
    for (int j = 0; j < 4; ++j) {
        v[j] = __expf(v[j] - mx);
        s += v[j];
    }
#pragma unroll
    for (int off = 32; off > 0; off >>= 1) s += __shfl_xor(s, off);
    if ((tid & 63) == 0) reds[tid >> 6] = s;
    __syncthreads();
    s = reds[0] + reds[1] + reds[2] + reds[3];
    const float inv = 1.0f / s;
#pragma unroll
    for (int j = 0; j < 4; ++j) attn[b * T_ + tid + 256 * j] = v[j] * inv;
}

// K4: context partials over t-segments. grid (D/256, NSEG, B), block 256
__global__ __launch_bounds__(256) void context_partial_kernel(
    const float* __restrict__ feat, const float* __restrict__ attn,
    float* __restrict__ part) {
    const int d   = blockIdx.x * 256 + threadIdx.x;
    const int seg = blockIdx.y;
    const int b   = blockIdx.z;
    const int t0  = seg * (T_ / NSEG);
    const float* fb = feat + ((size_t)b * T_ + t0) * D_ + d;
    const float* wb = attn + b * T_ + t0;
    float acc = 0.f;
#pragma unroll 8
    for (int t = 0; t < T_ / NSEG; ++t)
        acc = fmaf(wb[t], fb[(size_t)t * D_], acc);
    part[((b * NSEG + seg) * D_) + d] = acc;
}

// K5: reduce partials -> context. grid (B*D/256), block 256
__global__ __launch_bounds__(256) void context_reduce_kernel(
    const float* __restrict__ part, float* __restrict__ ctx) {
    const int i = blockIdx.x * 256 + threadIdx.x;  // [0, B*D)
    const int b = i >> 9;       // / D_
    const int d = i & (D_ - 1);
    float s = 0.f;
#pragma unroll
    for (int g = 0; g < NSEG; ++g) s += part[(b * NSEG + g) * D_ + d];
    ctx[i] = s;
}

extern "C" void kernel_launch(void* const* d_in, const int* in_sizes, int n_in,
                              void* d_out, int out_size, void* d_ws, size_t ws_size,
                              hipStream_t stream) {
    const float* feat   = (const float*)d_in[0];  // [B,T,D]
    const float* hidden = (const float*)d_in[1];  // [B,D]
    const float* W1w    = (const float*)d_in[2];  // [D,U]
    const float* W1b    = (const float*)d_in[3];  // [U]
    const float* W2w    = (const float*)d_in[4];  // [D,U]
    const float* W2b    = (const float*)d_in[5];  // [U]
    const float* Vw     = (const float*)d_in[6];  // [U]
    const float* Vb     = (const float*)d_in[7];  // [1]

    float* out_ctx  = (float*)d_out;            // [B,D] = 32768
    float* out_attn = out_ctx + B_ * D_;        // [B,T] = 65536

    float* ph     = (float*)d_ws;               // B*U floats
    float* logits = ph + B_ * U_;               // B*T floats
    float* part   = logits + B_ * T_;           // B*NSEG*D floats

    ph_kernel<<<dim3(U_ / 256, B_ / 8), 256, 0, stream>>>(hidden, W2w, W2b, W1b, ph);
    logits_kernel<<<dim3(T_ / TB, B_), 256, 0, stream>>>(feat, W1w, ph, Vw, Vb, logits);
    softmax_kernel<<<B_, 256, 0, stream>>>(logits, out_attn);
    context_partial_kernel<<<dim3(D_ / 256, NSEG, B_), 256, 0, stream>>>(feat, out_attn, part);
    context_reduce_kernel<<<B_ * D_ / 256, 256, 0, stream>>>(part, out_ctx);
}

// Round 2
// 483.634 us; speedup vs baseline: 2.7469x; 2.7469x over previous
//
#include <hip/hip_runtime.h>
#include <math.h>

#define B_ 64
#define T_ 1024
#define D_ 512
#define U_ 1024
#define NSEG 4

typedef __bf16 bf16x8 __attribute__((ext_vector_type(8)));
typedef float f32x4 __attribute__((ext_vector_type(4)));

__device__ __forceinline__ float fast_tanh(float x) {
    float ax = fabsf(x);
    float e = __expf(2.0f * ax);
    float r = 1.0f - __fdividef(2.0f, e + 1.0f);
    return copysignf(r, x);
}

// pack two floats to bf16x2 (round-half-up; inputs are sane, no NaN handling)
__device__ __forceinline__ unsigned f2bf_pk(float lo, float hi) {
    unsigned a = __float_as_uint(lo) + 0x8000u;
    unsigned b = __float_as_uint(hi) + 0x8000u;
    return (a >> 16) | (b & 0xffff0000u);
}

// K1: ph[b][u] = hidden[b,:]·W2[:,u] + W2_b[u] + W1_b[u]; grid (U/256, B), block 256
__global__ __launch_bounds__(256) void ph_kernel(
    const float* __restrict__ hidden, const float* __restrict__ W2,
    const float* __restrict__ W2b, const float* __restrict__ W1b,
    float* __restrict__ ph) {
    const int u = blockIdx.x * 256 + threadIdx.x;
    const int b = blockIdx.y;
    const float* h = hidden + b * D_;
    float acc = 0.f;
#pragma unroll 8
    for (int d = 0; d < D_; ++d) acc = fmaf(h[d], W2[(size_t)d * U_ + u], acc);
    ph[b * U_ + u] = acc + W2b[u] + W1b[u];
}

// K2: fused bf16-MFMA GEMM + tanh + V-dot -> logits[b][t]
// block 256 thr (4 waves), tile M=64 (t) x full K in LDS; u in 8 chunks of 128.
// Waves: wm = widx&1 (rows wm*32..+32), wn = widx>>1 (cols wn*64..+64).
__global__ __launch_bounds__(256, 2) void logits_mfma_kernel(
    const float* __restrict__ feat,   // [B,T,D]
    const float* __restrict__ W1,     // [D,U]
    const float* __restrict__ ph,     // [B,U] (both biases folded)
    const float* __restrict__ Vw,     // [U]
    const float* __restrict__ Vb,     // [1]
    float* __restrict__ logits) {     // [B,T]
    // A: [m][kg^ (m&7)] swizzle, 64 rows x 512 bf16 (1KB/row) -> balanced banks
    __shared__ unsigned short As[64 * 512];       // 64 KB
    // B: [u][kq ^ ((u>>1)&3)] swizzle, 128 rows x 32 bf16 (64B/row), dbuf
    __shared__ unsigned short Bs[2][128 * 32];    // 2 x 8 KB

    const int tid  = threadIdx.x;
    const int b    = blockIdx.y;
    const int t0   = blockIdx.x * 64;
    const int lane = tid & 63;
    const int widx = tid >> 6;
    const int wm = widx & 1, wn = widx >> 1;
    const int c = lane & 15, g = lane >> 4;

    // ---- stage A once: feat[b, t0..t0+64, :] fp32 -> bf16 swizzled LDS ----
    const float* fbase = feat + ((size_t)b * T_ + t0) * D_;
#pragma unroll 4
    for (int rep = 0; rep < 32; ++rep) {
        const int f4  = rep * 1024 + tid * 4;     // flat float index in 64x512
        const float4 v = *(const float4*)(fbase + f4);
        const int m   = f4 >> 9;
        const int col = f4 & 511;
        const int pkg = (col >> 3) ^ (m & 7);
        unsigned short* dst = &As[m * 512 + pkg * 8 + (col & 7)];
        uint2 w;
        w.x = f2bf_pk(v.x, v.y);
        w.y = f2bf_pk(v.z, v.w);
        *(uint2*)dst = w;   // ds_write_b64
    }

    // ---- B staging helpers (prefetch to regs, convert+write to LDS) ----
    const int bu = tid & 127;       // u within chunk
    const int kh = tid >> 7;        // k half (16 rows each)
    float pv[16];

    auto prefetchB = [&](int uc, int kc) {
        const float* src = W1 + (size_t)(kc + kh * 16) * U_ + uc + bu;
#pragma unroll
        for (int i = 0; i < 16; ++i) pv[i] = src[(size_t)i * U_];
    };
    auto writeB = [&](int buf) {
        const int f = (bu >> 1) & 3;
#pragma unroll
        for (int h = 0; h < 2; ++h) {
            const int pkq = (2 * kh + h) ^ f;
            uint4 w;
            w.x = f2bf_pk(pv[h * 8 + 0], pv[h * 8 + 1]);
            w.y = f2bf_pk(pv[h * 8 + 2], pv[h * 8 + 3]);
            w.z = f2bf_pk(pv[h * 8 + 4], pv[h * 8 + 5]);
            w.w = f2bf_pk(pv[h * 8 + 6], pv[h * 8 + 7]);
            *(uint4*)&Bs[buf][bu * 32 + pkq * 8] = w;  // ds_write_b128
        }
    };

    prefetchB(0, 0);
    writeB(0);
    __syncthreads();   // covers As too

    float lp[2][4];
#pragma unroll
    for (int mt = 0; mt < 2; ++mt)
#pragma unroll
        for (int r = 0; r < 4; ++r) lp[mt][r] = 0.f;

    int step = 0;
    for (int uci = 0; uci < 8; ++uci) {
        const int uc = uci * 128;
        f32x4 acc[2][4];
#pragma unroll
        for (int mt = 0; mt < 2; ++mt)
#pragma unroll
            for (int nt = 0; nt < 4; ++nt) acc[mt][nt] = (f32x4){0.f, 0.f, 0.f, 0.f};

        for (int ks = 0; ks < 16; ++ks) {
            const int cur = step & 1, nxt = cur ^ 1;
            const bool has_next = (ks < 15) || (uci < 7);
            if (has_next) {
                const int nuc = (ks < 15) ? uc : uc + 128;
                const int nkc = (ks < 15) ? (ks + 1) * 32 : 0;
                prefetchB(nuc, nkc);
            }
            // fragment reads (swizzled, bank-balanced)
            bf16x8 af[2], bfr[4];
#pragma unroll
            for (int mt = 0; mt < 2; ++mt) {
                const int m   = wm * 32 + mt * 16 + c;
                const int pkg = (ks * 4 + g) ^ (c & 7);
                af[mt] = *(const bf16x8*)&As[m * 512 + pkg * 8];
            }
            const int pkq = g ^ ((c >> 1) & 3);
#pragma unroll
            for (int nt = 0; nt < 4; ++nt) {
                const int u = wn * 64 + nt * 16 + c;
                bfr[nt] = *(const bf16x8*)&Bs[cur][u * 32 + pkq * 8];
            }
#pragma unroll
            for (int mt = 0; mt < 2; ++mt)
#pragma unroll
                for (int nt = 0; nt < 4; ++nt)
                    acc[mt][nt] = __builtin_amdgcn_mfma_f32_16x16x32_bf16(
                        af[mt], bfr[nt], acc[mt][nt], 0, 0, 0);
            if (has_next) writeB(nxt);
            __syncthreads();
            ++step;
        }

        // ---- fused epilogue for this u-chunk: tanh + V-dot into row partials ----
#pragma unroll
        for (int nt = 0; nt < 4; ++nt) {
            const int u    = uc + wn * 64 + nt * 16 + c;
            const float phv = ph[b * U_ + u];
            const float vw  = Vw[u];
#pragma unroll
            for (int mt = 0; mt < 2; ++mt) {
#pragma unroll
                for (int r = 0; r < 4; ++r) {
                    const float s = fast_tanh(acc[mt][nt][r] + phv);
                    lp[mt][r] = fmaf(vw, s, lp[mt][r]);
                }
            }
        }
    }

    // ---- reduce partials: over 16 lanes (c) sharing each row ----
#pragma unroll
    for (int mt = 0; mt < 2; ++mt)
#pragma unroll
        for (int r = 0; r < 4; ++r) {
            float v = lp[mt][r];
            v += __shfl_xor(v, 1);
            v += __shfl_xor(v, 2);
            v += __shfl_xor(v, 4);
            v += __shfl_xor(v, 8);
            lp[mt][r] = v;
        }
    // cross-wave (wn) sum via LDS scratch (reuse Bs)
    __syncthreads();
    float* scr = (float*)&Bs[0][0];
    if (wn == 1 && c == 0) {
#pragma unroll
        for (int mt = 0; mt < 2; ++mt)
#pragma unroll
            for (int r = 0; r < 4; ++r)
                scr[wm * 32 + mt * 16 + g * 4 + r] = lp[mt][r];
    }
    __syncthreads();
    if (wn == 0 && c == 0) {
        const float vb = Vb[0];
#pragma unroll
        for (int mt = 0; mt < 2; ++mt)
#pragma unroll
            for (int r = 0; r < 4; ++r) {
                const int row = wm * 32 + mt * 16 + g * 4 + r;
                logits[b * T_ + t0 + row] = lp[mt][r] + scr[row] + vb;
            }
    }
}

// K3: softmax over T per batch. grid B, block 256 (4 elems/thread)
__global__ __launch_bounds__(256) void softmax_kernel(
    const float* __restrict__ logits, float* __restrict__ attn) {
    const int b = blockIdx.x;
    const int tid = threadIdx.x;
    __shared__ float redm[4];
    __shared__ float reds[4];
    const float* lr = logits + b * T_;
    float v[4];
    float mx = -3.4e38f;
#pragma unroll
    for (int j = 0; j < 4; ++j) {
        v[j] = lr[tid + 256 * j];
        mx = fmaxf(mx, v[j]);
    }
#pragma unroll
    for (int off = 32; off > 0; off >>= 1) mx = fmaxf(mx, __shfl_xor(mx, off));
    if ((tid & 63) == 0) redm[tid >> 6] = mx;
    __syncthreads();
    mx = fmaxf(fmaxf(redm[0], redm[1]), fmaxf(redm[2], redm[3]));
    float s = 0.f;
#pragma unroll
    for (int j = 0; j < 4; ++j) {
        v[j] = __expf(v[j] - mx);
        s += v[j];
    }
#pragma unroll
    for (int off = 32; off > 0; off >>= 1) s += __shfl_xor(s, off);
    if ((tid & 63) == 0) reds[tid >> 6] = s;
    __syncthreads();
    s = reds[0] + reds[1] + reds[2] + reds[3];
    const float inv = 1.0f / s;
#pragma unroll
    for (int j = 0; j < 4; ++j) attn[b * T_ + tid + 256 * j] = v[j] * inv;
}

// K4: context partials over t-segments. grid (D/256, NSEG, B), block 256
__global__ __launch_bounds__(256) void context_partial_kernel(
    const float* __restrict__ feat, const float* __restrict__ attn,
    float* __restrict__ part) {
    const int d   = blockIdx.x * 256 + threadIdx.x;
    const int seg = blockIdx.y;
    const int b   = blockIdx.z;
    const int t0  = seg * (T_ / NSEG);
    const float* fb = feat + ((size_t)b * T_ + t0) * D_ + d;
    const float* wb = attn + b * T_ + t0;
    float acc = 0.f;
#pragma unroll 8
    for (int t = 0; t < T_ / NSEG; ++t)
        acc = fmaf(wb[t], fb[(size_t)t * D_], acc);
    part[((b * NSEG + seg) * D_) + d] = acc;
}

// K5: reduce partials -> context. grid (B*D/256), block 256
__global__ __launch_bounds__(256) void context_reduce_kernel(
    const float* __restrict__ part, float* __restrict__ ctx) {
    const int i = blockIdx.x * 256 + threadIdx.x;
    const int b = i >> 9;
    const int d = i & (D_ - 1);
    float s = 0.f;
#pragma unroll
    for (int g = 0; g < NSEG; ++g) s += part[(b * NSEG + g) * D_ + d];
    ctx[i] = s;
}

extern "C" void kernel_launch(void* const* d_in, const int* in_sizes, int n_in,
                              void* d_out, int out_size, void* d_ws, size_t ws_size,
                              hipStream_t stream) {
    const float* feat   = (const float*)d_in[0];
    const float* hidden = (const float*)d_in[1];
    const float* W1w    = (const float*)d_in[2];
    const float* W1b    = (const float*)d_in[3];
    const float* W2w    = (const float*)d_in[4];
    const float* W2b    = (const float*)d_in[5];
    const float* Vw     = (const float*)d_in[6];
    const float* Vb     = (const float*)d_in[7];

    float* out_ctx  = (float*)d_out;            // [B,D]
    float* out_attn = out_ctx + B_ * D_;        // [B,T]

    float* ph     = (float*)d_ws;               // B*U
    float* logits = ph + B_ * U_;               // B*T
    float* part   = logits + B_ * T_;           // B*NSEG*D

    ph_kernel<<<dim3(U_ / 256, B_), 256, 0, stream>>>(hidden, W2w, W2b, W1b, ph);
    logits_mfma_kernel<<<dim3(T_ / 64, B_), 256, 0, stream>>>(feat, W1w, ph, Vw, Vb, logits);
    softmax_kernel<<<B_, 256, 0, stream>>>(logits, out_attn);
    context_partial_kernel<<<dim3(D_ / 256, NSEG, B_), 256, 0, stream>>>(feat, out_attn, part);
    context_reduce_kernel<<<B_ * D_ / 256, 256, 0, stream>>>(part, out_ctx);
}

// Round 3
// 443.054 us; speedup vs baseline: 2.9985x; 1.0916x over previous
//
#include <hip/hip_runtime.h>
#include <math.h>

#define B_ 64
#define T_ 1024
#define D_ 512
#define U_ 1024
#define NSEG 4

typedef __bf16 bf16x8 __attribute__((ext_vector_type(8)));
typedef float f32x16 __attribute__((ext_vector_type(16)));
typedef unsigned int u32;

__device__ __forceinline__ float fast_tanh(float x) {
    float ax = fabsf(x);
    float e = __expf(2.0f * ax);
    float r = 1.0f - __fdividef(2.0f, e + 1.0f);
    return copysignf(r, x);
}

__device__ __forceinline__ u32 f2bf_pk(float lo, float hi) {
    u32 a = __float_as_uint(lo) + 0x8000u;
    u32 b = __float_as_uint(hi) + 0x8000u;
    return (a >> 16) | (b & 0xffff0000u);
}

// async global->LDS DMA, 16B per lane; dst is wave-uniform base (+lane*16 implicit)
__device__ __forceinline__ void dma16(const void* g, void* l) {
    __builtin_amdgcn_global_load_lds(
        (const __attribute__((address_space(1))) u32*)g,
        (__attribute__((address_space(3))) u32*)l, 16, 0, 0);
}

// K0: W1 [D][U] fp32 -> W1T [U][D] bf16. grid 256, block 256.
__global__ __launch_bounds__(256) void w1t_kernel(
    const float* __restrict__ W1, unsigned short* __restrict__ W1T) {
    const int gidx = blockIdx.x * 256 + threadIdx.x;   // 65536 total
    const int u  = gidx & (U_ - 1);
    const int d0 = (gidx >> 10) * 8;
    float f[8];
#pragma unroll
    for (int i = 0; i < 8; ++i) f[i] = W1[(size_t)(d0 + i) * U_ + u];
    uint4 w;
    w.x = f2bf_pk(f[0], f[1]);
    w.y = f2bf_pk(f[2], f[3]);
    w.z = f2bf_pk(f[4], f[5]);
    w.w = f2bf_pk(f[6], f[7]);
    *(uint4*)&W1T[(size_t)u * D_ + d0] = w;
}

// K1: ph[b][u] = hidden[b,:]·W2[:,u] + W2_b[u] + W1_b[u]; grid (U/256, B/8)
__global__ __launch_bounds__(256) void ph_kernel(
    const float* __restrict__ hidden, const float* __restrict__ W2,
    const float* __restrict__ W2b, const float* __restrict__ W1b,
    float* __restrict__ ph) {
    const int u = blockIdx.x * 256 + threadIdx.x;
    const int b0 = blockIdx.y * 8;
    float acc[8];
#pragma unroll
    for (int i = 0; i < 8; ++i) acc[i] = 0.f;
    for (int d = 0; d < D_; ++d) {
        const float w = W2[(size_t)d * U_ + u];
#pragma unroll
        for (int i = 0; i < 8; ++i)
            acc[i] = fmaf(hidden[(b0 + i) * D_ + d], w, acc[i]);
    }
    const float bias = W2b[u] + W1b[u];
#pragma unroll
    for (int i = 0; i < 8; ++i) ph[(b0 + i) * U_ + u] = acc[i] + bias;
}

// K2: fused bf16 32x32x16-MFMA GEMM + tanh + V-dot -> lpart[uh][b][t]
// 512 thr / 8 waves. Block tile: 128 t-rows x 512 u-cols (u-split x2 via blockIdx.z).
// Wave (wm=widx>>2, wn=widx&3): 64x128 (2x4 tiles of 32x32). K in 16 chunks of 32.
// LDS layout (A and B identical scheme): row r, k-group q (8 bf16):
//   addr = r*64 + (q ^ ((r>>2)&3))*16  -> conflict-free ds_read_b128 frag reads,
//   and each 16-row window is a lane-permutation of 64x16B slots -> DMA-compatible.
__global__ __launch_bounds__(512, 2) void logits_mfma_kernel(
    const float* __restrict__ feat,          // [B,T,D] fp32
    const unsigned short* __restrict__ W1T,  // [U,D] bf16
    const float* __restrict__ ph,            // [B,U] biases folded
    const float* __restrict__ Vw,            // [U]
    float* __restrict__ lpart) {             // [2][B][T]
    __shared__ __align__(16) char As[2][8192];    // 128 rows x 32 k bf16
    __shared__ __align__(16) char Bs[2][32768];   // 512 rows x 32 k bf16

    const int tid  = threadIdx.x;
    const int tt   = blockIdx.x;
    const int b    = blockIdx.y;
    const int uh   = blockIdx.z;
    const int t0   = tt * 128;
    const int uoff = uh * 512;
    const int lane = tid & 63;
    const int widx = tid >> 6;
    const int wm = widx >> 2, wn = widx & 3;
    const int l31 = lane & 31, g = lane >> 5;
    const int sw = (l31 >> 2) & 3;

    // ---- A manual staging mapping: thread -> (row=tid>>2, q=tid&3) ----
    const int arow = tid >> 2;
    const int aq   = tid & 3;
    const int ap   = aq ^ ((arow >> 2) & 3);
    const float* aSrc = feat + ((size_t)(b * T_ + t0 + arow)) * D_ + aq * 8;
    const int aDstOff = arow * 64 + ap * 16;

    // ---- B DMA per-lane source (swizzle folded into source address) ----
    const int bq = (lane & 3) ^ ((lane >> 4) & 3);
    const unsigned short* bSrcLane =
        W1T + (size_t)(uoff + (lane >> 2)) * D_ + bq * 8;

    float4 ra0, ra1;  // A prefetch regs (8 floats = one 16B bf16 slot)

    auto loadA = [&](int kc) {
        ra0 = *(const float4*)(aSrc + kc);
        ra1 = *(const float4*)(aSrc + kc + 4);
    };
    auto writeA = [&](int buf) {
        uint4 w;
        w.x = f2bf_pk(ra0.x, ra0.y);
        w.y = f2bf_pk(ra0.z, ra0.w);
        w.z = f2bf_pk(ra1.x, ra1.y);
        w.w = f2bf_pk(ra1.z, ra1.w);
        *(uint4*)&As[buf][aDstOff] = w;
    };
    auto issueB = [&](int buf, int kc) {
#pragma unroll
        for (int j = 0; j < 4; ++j) {
            const int v = widx * 4 + j;           // u-window (16 rows), wave-uniform
            dma16(bSrcLane + (size_t)v * 16 * D_ + kc, &Bs[buf][v * 1024]);
        }
    };

    f32x16 acc[2][4];
#pragma unroll
    for (int mt = 0; mt < 2; ++mt)
#pragma unroll
        for (int nt = 0; nt < 4; ++nt) acc[mt][nt] = (f32x16)(0.f);

    // ---- prologue ----
    loadA(0);
    issueB(0, 0);
    writeA(0);
    loadA(32);
    __syncthreads();

    // ---- main K loop: 16 iters of k32 ----
    for (int kt = 0; kt < 16; ++kt) {
        const int cur = kt & 1, nxt = cur ^ 1;
        if (kt < 15) {
            issueB(nxt, (kt + 1) * 32);
            writeA(nxt);                 // regs loaded one iter ago
        }
        if (kt < 14) loadA((kt + 2) * 32);

        const char* Ab = As[cur];
        const char* Bb = Bs[cur];
#pragma unroll
        for (int ks = 0; ks < 2; ++ks) {
            const int qsw = ((2 * ks + g) ^ sw) << 4;
            bf16x8 af[2], bfr[4];
#pragma unroll
            for (int mt = 0; mt < 2; ++mt)
                af[mt] = *(const bf16x8*)(Ab + (wm * 64 + mt * 32 + l31) * 64 + qsw);
#pragma unroll
            for (int nt = 0; nt < 4; ++nt)
                bfr[nt] = *(const bf16x8*)(Bb + (wn * 128 + nt * 32 + l31) * 64 + qsw);
#pragma unroll
            for (int mt = 0; mt < 2; ++mt)
#pragma unroll
                for (int nt = 0; nt < 4; ++nt)
                    acc[mt][nt] = __builtin_amdgcn_mfma_f32_32x32x16_bf16(
                        af[mt], bfr[nt], acc[mt][nt], 0, 0, 0);
        }
        __syncthreads();
    }

    // ---- fused epilogue: tanh + V-dot, reduce over u ----
    float lp[2][16];
#pragma unroll
    for (int mt = 0; mt < 2; ++mt)
#pragma unroll
        for (int r = 0; r < 16; ++r) lp[mt][r] = 0.f;

#pragma unroll
    for (int nt = 0; nt < 4; ++nt) {
        const int u = uoff + wn * 128 + nt * 32 + l31;
        const float phv = ph[b * U_ + u];
        const float vw  = Vw[u];
#pragma unroll
        for (int mt = 0; mt < 2; ++mt)
#pragma unroll
            for (int r = 0; r < 16; ++r)
                lp[mt][r] = fmaf(vw, fast_tanh(acc[mt][nt][r] + phv), lp[mt][r]);
    }
    // sum over the 32 columns held by lanes (l&31); row identity kept (bit5=g)
#pragma unroll
    for (int mt = 0; mt < 2; ++mt)
#pragma unroll
        for (int r = 0; r < 16; ++r) {
            float v = lp[mt][r];
            v += __shfl_xor(v, 1);
            v += __shfl_xor(v, 2);
            v += __shfl_xor(v, 4);
            v += __shfl_xor(v, 8);
            v += __shfl_xor(v, 16);
            lp[mt][r] = v;
        }
    __syncthreads();
    float* scr = (float*)&As[0][0];   // [128 rows][4 wn]
    if (l31 == 0) {
#pragma unroll
        for (int mt = 0; mt < 2; ++mt)
#pragma unroll
            for (int r = 0; r < 16; ++r) {
                const int row = wm * 64 + mt * 32 + (r & 3) + 8 * (r >> 2) + 4 * g;
                scr[row * 4 + wn] = lp[mt][r];
            }
    }
    __syncthreads();
    if (tid < 128) {
        const float s = scr[tid * 4 + 0] + scr[tid * 4 + 1] +
                        scr[tid * 4 + 2] + scr[tid * 4 + 3];
        lpart[((size_t)uh * B_ + b) * T_ + t0 + tid] = s;
    }
}

// K3: softmax over T per batch from 2 u-half partials (Vb cancels in softmax)
__global__ __launch_bounds__(256) void softmax2_kernel(
    const float* __restrict__ lp0, const float* __restrict__ lp1,
    float* __restrict__ attn) {
    const int b = blockIdx.x;
    const int tid = threadIdx.x;
    __shared__ float redm[4];
    __shared__ float reds[4];
    float v[4];
    float mx = -3.4e38f;
#pragma unroll
    for (int j = 0; j < 4; ++j) {
        const int x = b * T_ + tid + 256 * j;
        v[j] = lp0[x] + lp1[x];
        mx = fmaxf(mx, v[j]);
    }
#pragma unroll
    for (int off = 32; off > 0; off >>= 1) mx = fmaxf(mx, __shfl_xor(mx, off));
    if ((tid & 63) == 0) redm[tid >> 6] = mx;
    __syncthreads();
    mx = fmaxf(fmaxf(redm[0], redm[1]), fmaxf(redm[2], redm[3]));
    float s = 0.f;
#pragma unroll
    for (int j = 0; j < 4; ++j) {
        v[j] = __expf(v[j] - mx);
        s += v[j];
    }
#pragma unroll
    for (int off = 32; off > 0; off >>= 1) s += __shfl_xor(s, off);
    if ((tid & 63) == 0) reds[tid >> 6] = s;
    __syncthreads();
    s = reds[0] + reds[1] + reds[2] + reds[3];
    const float inv = 1.0f / s;
#pragma unroll
    for (int j = 0; j < 4; ++j) attn[b * T_ + tid + 256 * j] = v[j] * inv;
}

// K4: context partials over t-segments. grid (D/256, NSEG, B)
__global__ __launch_bounds__(256) void context_partial_kernel(
    const float* __restrict__ feat, const float* __restrict__ attn,
    float* __restrict__ part) {
    const int d   = blockIdx.x * 256 + threadIdx.x;
    const int seg = blockIdx.y;
    const int b   = blockIdx.z;
    const int t0  = seg * (T_ / NSEG);
    const float* fb = feat + ((size_t)b * T_ + t0) * D_ + d;
    const float* wb = attn + b * T_ + t0;
    float acc = 0.f;
#pragma unroll 8
    for (int t = 0; t < T_ / NSEG; ++t)
        acc = fmaf(wb[t], fb[(size_t)t * D_], acc);
    part[((b * NSEG + seg) * D_) + d] = acc;
}

// K5: reduce partials -> context
__global__ __launch_bounds__(256) void context_reduce_kernel(
    const float* __restrict__ part, float* __restrict__ ctx) {
    const int i = blockIdx.x * 256 + threadIdx.x;
    const int b = i >> 9;
    const int d = i & (D_ - 1);
    float s = 0.f;
#pragma unroll
    for (int g = 0; g < NSEG; ++g) s += part[(b * NSEG + g) * D_ + d];
    ctx[i] = s;
}

extern "C" void kernel_launch(void* const* d_in, const int* in_sizes, int n_in,
                              void* d_out, int out_size, void* d_ws, size_t ws_size,
                              hipStream_t stream) {
    const float* feat   = (const float*)d_in[0];
    const float* hidden = (const float*)d_in[1];
    const float* W1w    = (const float*)d_in[2];
    const float* W1b    = (const float*)d_in[3];
    const float* W2w    = (const float*)d_in[4];
    const float* W2b    = (const float*)d_in[5];
    const float* Vw     = (const float*)d_in[6];
    // V_b (d_in[7]) cancels in softmax and does not affect context -> unused.

    float* out_ctx  = (float*)d_out;             // [B,D]
    float* out_attn = out_ctx + B_ * D_;         // [B,T]

    unsigned short* W1T = (unsigned short*)d_ws;             // U*D bf16 = 1 MB
    float* ph     = (float*)(W1T + (size_t)U_ * D_);         // B*U
    float* lpart  = ph + B_ * U_;                            // 2*B*T
    float* part   = lpart + 2 * B_ * T_;                     // B*NSEG*D

    w1t_kernel<<<256, 256, 0, stream>>>(W1w, W1T);
    ph_kernel<<<dim3(U_ / 256, B_ / 8), 256, 0, stream>>>(hidden, W2w, W2b, W1b, ph);
    logits_mfma_kernel<<<dim3(T_ / 128, B_, 2), 512, 0, stream>>>(
        feat, W1T, ph, Vw, lpart);
    softmax2_kernel<<<B_, 256, 0, stream>>>(lpart, lpart + B_ * T_, out_attn);
    context_partial_kernel<<<dim3(D_ / 256, NSEG, B_), 256, 0, stream>>>(
        feat, out_attn, part);
    context_reduce_kernel<<<B_ * D_ / 256, 256, 0, stream>>>(part, out_ctx);
}

// Round 4
// 382.082 us; speedup vs baseline: 3.4770x; 1.1596x over previous
//
#include <hip/hip_runtime.h>
#include <math.h>

#define B_ 64
#define T_ 1024
#define D_ 512
#define U_ 1024

typedef __bf16 bf16x8 __attribute__((ext_vector_type(8)));
typedef float f32x16 __attribute__((ext_vector_type(16)));
typedef unsigned int u32;

__device__ __forceinline__ float fast_tanh(float x) {
    float ax = fabsf(x);
    float e = __expf(2.0f * ax);
    float r = 1.0f - __fdividef(2.0f, e + 1.0f);
    return copysignf(r, x);
}

__device__ __forceinline__ u32 f2bf_pk(float lo, float hi) {
    u32 a = __float_as_uint(lo) + 0x8000u;
    u32 b = __float_as_uint(hi) + 0x8000u;
    return (a >> 16) | (b & 0xffff0000u);
}

__device__ __forceinline__ void dma16(const void* g, void* l) {
    __builtin_amdgcn_global_load_lds(
        (const __attribute__((address_space(1))) u32*)g,
        (__attribute__((address_space(3))) u32*)l, 16, 0, 0);
}

// K0: W1 [D][U] fp32 -> W1T [U][D] bf16
__global__ __launch_bounds__(256) void w1t_kernel(
    const float* __restrict__ W1, unsigned short* __restrict__ W1T) {
    const int gidx = blockIdx.x * 256 + threadIdx.x;
    const int u  = gidx & (U_ - 1);
    const int d0 = (gidx >> 10) * 8;
    float f[8];
#pragma unroll
    for (int i = 0; i < 8; ++i) f[i] = W1[(size_t)(d0 + i) * U_ + u];
    uint4 w;
    w.x = f2bf_pk(f[0], f[1]);
    w.y = f2bf_pk(f[2], f[3]);
    w.z = f2bf_pk(f[4], f[5]);
    w.w = f2bf_pk(f[6], f[7]);
    *(uint4*)&W1T[(size_t)u * D_ + d0] = w;
}

// K1: ph[b][u] = hidden[b,:]·W2[:,u] + W2_b[u] + W1_b[u]; grid (U/256, B) = 256 blocks
__global__ __launch_bounds__(256) void ph_kernel(
    const float* __restrict__ hidden, const float* __restrict__ W2,
    const float* __restrict__ W2b, const float* __restrict__ W1b,
    float* __restrict__ ph) {
    const int u = blockIdx.x * 256 + threadIdx.x;
    const int b = blockIdx.y;
    const float* h = hidden + b * D_;
    float acc = 0.f;
#pragma unroll 8
    for (int d = 0; d < D_; ++d) acc = fmaf(h[d], W2[(size_t)d * U_ + u], acc);
    ph[b * U_ + u] = acc + W2b[u] + W1b[u];
}

// K2: fused bf16 32x32x16-MFMA GEMM + tanh + V-dot -> lpart[uh][b][t]
// 512 thr / 8 waves. Block tile 128 t x 256 u; u-split x4. Wave 64x64 (2x2 of 32x32),
// acc=64 regs -> with __launch_bounds__(512,4) two blocks/CU co-resident.
// LDS swizzle (A,B same): row r, k-group q: addr = r*64 + (q ^ ((r>>2)&3))*16
// -> conflict-free b128 frag reads (verified R3: 0 conflicts) and DMA-expressible.
__global__ __launch_bounds__(512, 4) void logits_mfma_kernel(
    const float* __restrict__ feat,          // [B,T,D] fp32
    const unsigned short* __restrict__ W1T,  // [U,D] bf16
    const float* __restrict__ ph,            // [B,U] biases folded
    const float* __restrict__ Vw,            // [U]
    float* __restrict__ lpart) {             // [4][B][T]
    __shared__ __align__(16) char As[2][8192];    // 128 rows x 32 k bf16
    __shared__ __align__(16) char Bs[2][16384];   // 256 rows x 32 k bf16

    const int tid  = threadIdx.x;
    const int gx   = blockIdx.x;       // 32: uh fastest so A-sharing blocks co-dispatch
    const int uh   = gx & 3;
    const int tt   = gx >> 2;
    const int b    = blockIdx.y;
    const int t0   = tt * 128;
    const int uoff = uh * 256;
    const int lane = tid & 63;
    const int widx = tid >> 6;
    const int wm = widx >> 2, wn = widx & 3;
    const int l31 = lane & 31, g = lane >> 5;
    const int sw = (l31 >> 2) & 3;

    // A staging: thread -> one 16B slot: row r=tid>>2 (0..127), q=tid&3
    const int arow = tid >> 2;
    const int aq   = tid & 3;
    const float* aSrc = feat + ((size_t)(b * T_ + t0 + arow)) * D_ + aq * 8;
    const int aDstOff = arow * 64 + (aq ^ ((arow >> 2) & 3)) * 16;

    // B DMA: swizzle folded into per-lane source address
    const int bq = (lane & 3) ^ ((lane >> 4) & 3);
    const unsigned short* bSrcLane =
        W1T + (size_t)(uoff + (lane >> 2)) * D_ + bq * 8;

    float4 ra0, ra1;
    auto loadA = [&](int kc) {
        ra0 = *(const float4*)(aSrc + kc);
        ra1 = *(const float4*)(aSrc + kc + 4);
    };
    auto writeA = [&](int buf) {
        uint4 w;
        w.x = f2bf_pk(ra0.x, ra0.y);
        w.y = f2bf_pk(ra0.z, ra0.w);
        w.z = f2bf_pk(ra1.x, ra1.y);
        w.w = f2bf_pk(ra1.z, ra1.w);
        *(uint4*)&As[buf][aDstOff] = w;
    };
    auto issueB = [&](int buf, int kc) {
#pragma unroll
        for (int j = 0; j < 2; ++j) {
            const int v = widx * 2 + j;   // 16 slots of 16 rows, wave-uniform
            dma16(bSrcLane + (size_t)v * 16 * D_ + kc, &Bs[buf][v * 1024]);
        }
    };

    f32x16 acc[2][2];
#pragma unroll
    for (int mt = 0; mt < 2; ++mt)
#pragma unroll
        for (int nt = 0; nt < 2; ++nt) acc[mt][nt] = (f32x16)(0.f);

    loadA(0);
    issueB(0, 0);
    writeA(0);
    loadA(32);
    __syncthreads();

    for (int kt = 0; kt < 16; ++kt) {
        const int cur = kt & 1, nxt = cur ^ 1;
        if (kt < 15) {
            issueB(nxt, (kt + 1) * 32);
            writeA(nxt);
        }
        if (kt < 14) loadA((kt + 2) * 32);

        const char* Ab = As[cur];
        const char* Bb = Bs[cur];
#pragma unroll
        for (int ks = 0; ks < 2; ++ks) {
            const int qsw = ((2 * ks + g) ^ sw) << 4;
            bf16x8 af[2], bfr[2];
#pragma unroll
            for (int mt = 0; mt < 2; ++mt)
                af[mt] = *(const bf16x8*)(Ab + (wm * 64 + mt * 32 + l31) * 64 + qsw);
#pragma unroll
            for (int nt = 0; nt < 2; ++nt)
                bfr[nt] = *(const bf16x8*)(Bb + (wn * 64 + nt * 32 + l31) * 64 + qsw);
#pragma unroll
            for (int mt = 0; mt < 2; ++mt)
#pragma unroll
                for (int nt = 0; nt < 2; ++nt)
                    acc[mt][nt] = __builtin_amdgcn_mfma_f32_32x32x16_bf16(
                        af[mt], bfr[nt], acc[mt][nt], 0, 0, 0);
        }
        __syncthreads();
    }

    // fused epilogue: tanh + V-dot, reduce over u
    float lp[2][16];
#pragma unroll
    for (int mt = 0; mt < 2; ++mt)
#pragma unroll
        for (int r = 0; r < 16; ++r) lp[mt][r] = 0.f;

#pragma unroll
    for (int nt = 0; nt < 2; ++nt) {
        const int u = uoff + wn * 64 + nt * 32 + l31;
        const float phv = ph[b * U_ + u];
        const float vw  = Vw[u];
#pragma unroll
        for (int mt = 0; mt < 2; ++mt)
#pragma unroll
            for (int r = 0; r < 16; ++r)
                lp[mt][r] = fmaf(vw, fast_tanh(acc[mt][nt][r] + phv), lp[mt][r]);
    }
#pragma unroll
    for (int mt = 0; mt < 2; ++mt)
#pragma unroll
        for (int r = 0; r < 16; ++r) {
            float v = lp[mt][r];
            v += __shfl_xor(v, 1);
            v += __shfl_xor(v, 2);
            v += __shfl_xor(v, 4);
            v += __shfl_xor(v, 8);
            v += __shfl_xor(v, 16);
            lp[mt][r] = v;
        }
    __syncthreads();
    float* scr = (float*)&As[0][0];   // [128 rows][4 wn]
    if (l31 == 0) {
#pragma unroll
        for (int mt = 0; mt < 2; ++mt)
#pragma unroll
            for (int r = 0; r < 16; ++r) {
                const int row = wm * 64 + mt * 32 + (r & 3) + 8 * (r >> 2) + 4 * g;
                scr[row * 4 + wn] = lp[mt][r];
            }
    }
    __syncthreads();
    if (tid < 128) {
        const float s = scr[tid * 4 + 0] + scr[tid * 4 + 1] +
                        scr[tid * 4 + 2] + scr[tid * 4 + 3];
        lpart[((size_t)uh * B_ + b) * T_ + t0 + tid] = s;
    }
}

// K3: softmax over T from 4 u-quarter partials (Vb cancels)
__global__ __launch_bounds__(256) void softmax4_kernel(
    const float* __restrict__ lp, float* __restrict__ attn) {
    const int b = blockIdx.x;
    const int tid = threadIdx.x;
    __shared__ float redm[4];
    __shared__ float reds[4];
    float v[4];
    float mx = -3.4e38f;
#pragma unroll
    for (int j = 0; j < 4; ++j) {
        const int x = b * T_ + tid + 256 * j;
        v[j] = lp[x] + lp[B_ * T_ + x] + lp[2 * B_ * T_ + x] + lp[3 * B_ * T_ + x];
        mx = fmaxf(mx, v[j]);
    }
#pragma unroll
    for (int off = 32; off > 0; off >>= 1) mx = fmaxf(mx, __shfl_xor(mx, off));
    if ((tid & 63) == 0) redm[tid >> 6] = mx;
    __syncthreads();
    mx = fmaxf(fmaxf(redm[0], redm[1]), fmaxf(redm[2], redm[3]));
    float s = 0.f;
#pragma unroll
    for (int j = 0; j < 4; ++j) {
        v[j] = __expf(v[j] - mx);
        s += v[j];
    }
#pragma unroll
    for (int off = 32; off > 0; off >>= 1) s += __shfl_xor(s, off);
    if ((tid & 63) == 0) reds[tid >> 6] = s;
    __syncthreads();
    s = reds[0] + reds[1] + reds[2] + reds[3];
    const float inv = 1.0f / s;
#pragma unroll
    for (int j = 0; j < 4; ++j) attn[b * T_ + tid + 256 * j] = v[j] * inv;
}

// K4: context partials, float4, 16 t-segments. grid (8, B), block 256
__global__ __launch_bounds__(256) void context_partial_kernel(
    const float* __restrict__ feat, const float* __restrict__ attn,
    float* __restrict__ part) {
    const int b   = blockIdx.y;
    const int seg = blockIdx.x;
    const int d4  = (threadIdx.x & 127) * 4;
    const int h   = threadIdx.x >> 7;
    const int t0  = seg * 128 + h * 64;
    const float* fb = feat + ((size_t)b * T_ + t0) * D_ + d4;
    const float* wb = attn + b * T_ + t0;
    float4 acc = {0.f, 0.f, 0.f, 0.f};
#pragma unroll 4
    for (int t = 0; t < 64; ++t) {
        const float w  = wb[t];
        const float4 f = *(const float4*)&fb[(size_t)t * D_];
        acc.x = fmaf(w, f.x, acc.x);
        acc.y = fmaf(w, f.y, acc.y);
        acc.z = fmaf(w, f.z, acc.z);
        acc.w = fmaf(w, f.w, acc.w);
    }
    *(float4*)&part[((size_t)(b * 16 + seg * 2 + h)) * D_ + d4] = acc;
}

// K5: reduce 16 partials -> context. grid (B*D/256)
__global__ __launch_bounds__(256) void context_reduce_kernel(
    const float* __restrict__ part, float* __restrict__ ctx) {
    const int i = blockIdx.x * 256 + threadIdx.x;
    const int b = i >> 9;
    const int d = i & (D_ - 1);
    float s = 0.f;
#pragma unroll
    for (int g = 0; g < 16; ++g) s += part[((size_t)(b * 16 + g)) * D_ + d];
    ctx[i] = s;
}

extern "C" void kernel_launch(void* const* d_in, const int* in_sizes, int n_in,
                              void* d_out, int out_size, void* d_ws, size_t ws_size,
                              hipStream_t stream) {
    const float* feat   = (const float*)d_in[0];
    const float* hidden = (const float*)d_in[1];
    const float* W1w    = (const float*)d_in[2];
    const float* W1b    = (const float*)d_in[3];
    const float* W2w    = (const float*)d_in[4];
    const float* W2b    = (const float*)d_in[5];
    const float* Vw     = (const float*)d_in[6];
    // V_b cancels in softmax and doesn't affect context.

    float* out_ctx  = (float*)d_out;             // [B,D]
    float* out_attn = out_ctx + B_ * D_;         // [B,T]

    unsigned short* W1T = (unsigned short*)d_ws;             // U*D bf16 = 1 MB
    float* ph     = (float*)(W1T + (size_t)U_ * D_);         // B*U
    float* lpart  = ph + B_ * U_;                            // 4*B*T
    float* part   = lpart + 4 * B_ * T_;                     // B*16*D

    w1t_kernel<<<256, 256, 0, stream>>>(W1w, W1T);
    ph_kernel<<<dim3(U_ / 256, B_), 256, 0, stream>>>(hidden, W2w, W2b, W1b, ph);
    logits_mfma_kernel<<<dim3(32, B_), 512, 0, stream>>>(feat, W1T, ph, Vw, lpart);
    softmax4_kernel<<<B_, 256, 0, stream>>>(lpart, out_attn);
    context_partial_kernel<<<dim3(8, B_), 256, 0, stream>>>(feat, out_attn, part);
    context_reduce_kernel<<<B_ * D_ / 256, 256, 0, stream>>>(part, out_ctx);
}